// Round 2
// baseline (480.820 us; speedup 1.0000x reference)
//
#include <hip/hip_runtime.h>

// Attention_72275709657473 — full MHA block on gfx950.
// Pipeline: cast(fp32->bf16) -> QKV proj GEMM (bf16 MFMA) -> causal flash attn -> out proj.
// Flash: TRANSPOSED formulation (S^T = K Q^T, O^T = V^T P^T), DS-pipe-minimized:
//   * PV uses v_mfma_f32_16x16x16_bf16: its B-frag k-index (g*4+j) matches the QK C-layout
//     row index (g*4+r) exactly, so packed P feeds PV IN-LANE — the 16 ds_bpermute
//     P-broadcasts per chunk of the previous version are gone (DS pipe was the CU-wide
//     bottleneck: occupancy 17->34% changed nothing, MfmaUtil stuck at 9%).
//   * hi/lo q-tile computes fused per chunk: Kt/Vt fragments read ONCE, serve both tiles.
//   * triangle pairing: block (p,bh) owns q-tiles {p, 15-p} (balanced grid, 512 blocks)
//   * double-buffered LDS (64KB, 2 blocks/CU), async16 K staging, reg-staged V transpose.
//   * 8 waves/block: wave owns 16 rows of hi tile + 16 rows of lo tile.
// ws layout: Xq/Xk/Xv bf16 (3x16MB) | Wq/Wk/Wv/Wo bf16 (4x2MB) | Q/K/V bf16 (3x16MB).
// Og (attn output, bf16) reuses the Xq region. Total ~104MB.

#define E 1024
#define HEADS 16
#define HD 64
#define SEQ 2048
#define BATCH 4
#define MROWS (BATCH * SEQ) /* 8192 */

typedef __bf16 bf16x8 __attribute__((ext_vector_type(8)));
typedef __bf16 bf16x4 __attribute__((ext_vector_type(4)));
typedef __bf16 bf16x2 __attribute__((ext_vector_type(2)));
typedef float f32x4 __attribute__((ext_vector_type(4)));
typedef short short4v __attribute__((ext_vector_type(4)));
typedef unsigned short ushort8v __attribute__((ext_vector_type(8)));

typedef __attribute__((address_space(1))) void gvoid;
typedef __attribute__((address_space(3))) void lvoid;

__device__ __forceinline__ void async16(const void* g, void* l) {
  __builtin_amdgcn_global_load_lds((gvoid*)g, (lvoid*)l, 16, 0, 0);
}

__device__ __forceinline__ unsigned short f2bf(float f) {
  union { float f; unsigned int u; } v;
  v.f = f;
  unsigned int r = v.u + 0x7FFFu + ((v.u >> 16) & 1u); // round-to-nearest-even
  return (unsigned short)(r >> 16);
}

__device__ __forceinline__ f32x4 mfma16(bf16x4 a, bf16x4 b, f32x4 c) {
  return __builtin_amdgcn_mfma_f32_16x16x16bf16_1k(
      __builtin_bit_cast(short4v, a), __builtin_bit_cast(short4v, b), c, 0, 0, 0);
}

__device__ __forceinline__ void store_out(unsigned short* p, float v) { *p = f2bf(v); }
__device__ __forceinline__ void store_out(float* p, float v) { *p = v; }

// ---------------- cast kernels ----------------
struct CastArgs {
  const float* src[4];
  unsigned short* dst[4];
  int n;
};

__global__ __launch_bounds__(256) void cast_kernel(CastArgs a) {
  const float* s = a.src[blockIdx.z];
  unsigned short* d = a.dst[blockIdx.z];
  const int n = a.n;
  const int stride = gridDim.x * blockDim.x * 4;
  for (int i = (blockIdx.x * blockDim.x + threadIdx.x) * 4; i < n; i += stride) {
    float4 v = *(const float4*)(s + i);
    ushort4 o;
    o.x = f2bf(v.x); o.y = f2bf(v.y); o.z = f2bf(v.z); o.w = f2bf(v.w);
    *(ushort4*)(d + i) = o;
  }
}

// ---------------- GEMM: C[M,N] = A[M,K] @ W[N,K]^T, epilogue (acc+bias)*scale ----------------
// 128x128 tile, BK=64, 256 threads = 4 waves in 2x2, each wave 64x64 (4x4 of 16x16x32 MFMA).
// LDS tiles row-major 128x64 bf16, XOR chunk swizzle: chunk c of row r at slot c^(r&7).
template <typename OutT>
__device__ __forceinline__ void gemm_body(const unsigned short* __restrict__ A,
                                          const unsigned short* __restrict__ W,
                                          const float* __restrict__ bias,
                                          OutT* __restrict__ out, float scale) {
  __shared__ unsigned short At[128 * 64];
  __shared__ unsigned short Wt[128 * 64];
  const int tid = threadIdx.x;
  const int lane = tid & 63;
  const int wv = tid >> 6;
  const int wm = wv & 1, wn = wv >> 1;
  const int li = lane & 15, g = lane >> 4;
  const int m0 = blockIdx.x * 128, n0 = blockIdx.y * 128;
  f32x4 acc[4][4] = {};

  for (int k0 = 0; k0 < E; k0 += 64) {
    __syncthreads();
#pragma unroll
    for (int i = 0; i < 4; ++i) {
      int c = tid + 256 * i;
      int row = c >> 3, slot = c & 7;
      int gc = slot ^ (row & 7);
      async16(A + (size_t)(m0 + row) * E + k0 + gc * 8, &At[c * 8]);
      async16(W + (size_t)(n0 + row) * E + k0 + gc * 8, &Wt[c * 8]);
    }
    asm volatile("s_waitcnt vmcnt(0)" ::: "memory");
    __syncthreads();
#pragma unroll
    for (int kk = 0; kk < 2; ++kk) {
      bf16x8 af[4], bfr[4];
#pragma unroll
      for (int mt = 0; mt < 4; ++mt) {
        int r = wm * 64 + mt * 16 + li;
        int slot = (kk * 4 + g) ^ (r & 7);
        af[mt] = *(const bf16x8*)&At[r * 64 + slot * 8];
      }
#pragma unroll
      for (int nt = 0; nt < 4; ++nt) {
        int r = wn * 64 + nt * 16 + li;
        int slot = (kk * 4 + g) ^ (r & 7);
        bfr[nt] = *(const bf16x8*)&Wt[r * 64 + slot * 8];
      }
#pragma unroll
      for (int mt = 0; mt < 4; ++mt)
#pragma unroll
        for (int nt = 0; nt < 4; ++nt)
          acc[mt][nt] =
              __builtin_amdgcn_mfma_f32_16x16x32_bf16(af[mt], bfr[nt], acc[mt][nt], 0, 0, 0);
    }
  }

#pragma unroll
  for (int nt = 0; nt < 4; ++nt) {
    int col = n0 + wn * 64 + nt * 16 + li;
    float bv = bias[col];
#pragma unroll
    for (int mt = 0; mt < 4; ++mt) {
#pragma unroll
      for (int r = 0; r < 4; ++r) {
        int row = m0 + wm * 64 + mt * 16 + g * 4 + r;
        store_out(&out[(size_t)row * E + col], (acc[mt][nt][r] + bv) * scale);
      }
    }
  }
}

struct QkvArgs {
  const unsigned short* A[3];
  const unsigned short* W[3];
  const float* bias[3];
  unsigned short* out[3];
  float scale[3];
};

__global__ __launch_bounds__(256) void gemm_qkv(QkvArgs p) {
  const int z = blockIdx.z;
  gemm_body<unsigned short>(p.A[z], p.W[z], p.bias[z], p.out[z], p.scale[z]);
}

__global__ __launch_bounds__(256) void gemm_out_k(const unsigned short* __restrict__ A,
                                                  const unsigned short* __restrict__ W,
                                                  const float* __restrict__ bias,
                                                  float* __restrict__ out) {
  gemm_body<float>(A, W, bias, out, 1.0f);
}

// ---------------- causal flash attention (transposed, paired, fused hi/lo, in-lane PV) ----
// grid (8 pairs, 64 b*h), 512 threads = 8 waves; wave w owns rows [16w,16w+16) of BOTH
// q-tiles {p, 15-p}. Per staged 128-key tile j (0..15-p), per 64-key chunk: Kt/Vt fragments
// read once and shared by hi (always) and lo (j<=p) tiles. QK = 16x16x32 MFMA; PV =
// 16x16x16 MFMA whose B-frag takes packed P straight from the QK C-layout (no shuffles).
__global__ __launch_bounds__(512, 4) void flash_kernel(const unsigned short* __restrict__ Qb,
                                                       const unsigned short* __restrict__ Kb,
                                                       const unsigned short* __restrict__ Vb,
                                                       unsigned short* __restrict__ Ob) {
  __shared__ unsigned short Kt[2][128 * 64];
  __shared__ unsigned short Vt[2][64 * 128];
  const int p = blockIdx.x;  // 0..7
  const int bh = blockIdx.y;
  const int b = bh >> 4, h16 = bh & 15;
  const size_t base = (size_t)b * SEQ * E + (size_t)h16 * HD;
  const unsigned short* Qp = Qb + base;
  const unsigned short* Kp = Kb + base;
  const unsigned short* Vp = Vb + base;
  unsigned short* Op = Ob + base;
  const int tid = threadIdx.x, lane = tid & 63, wv = tid >> 6; // wv in 0..7
  const int li = lane & 15, g = lane >> 4;
  const int qlo = p, qhi = 15 - p;

  // Q fragments (B-operand layout): lane holds Q[q = li][d = kk*32 + g*8 .. +7]
  bf16x8 qfL[2], qfH[2];
#pragma unroll
  for (int kk = 0; kk < 2; ++kk) {
    int rl = qlo * 128 + wv * 16 + li;
    int rh = qhi * 128 + wv * 16 + li;
    qfL[kk] = *(const bf16x8*)(Qp + (size_t)rl * E + kk * 32 + g * 8);
    qfH[kk] = *(const bf16x8*)(Qp + (size_t)rh * E + kk * 32 + g * 8);
  }

  f32x4 oaL[4] = {}, oaH[4] = {}; // O^T C-layout: col=q=li, row=d=g*4+r
  float miL = -1e30f, lsL = 0.0f;
  float miH = -1e30f, lsH = 0.0f;

  ushort8v vv[2]; // V prefetch registers

  auto loadV = [&](int j) {
#pragma unroll
    for (int i = 0; i < 2; ++i) {
      int c = tid + 512 * i;
      int key = c & 127, db = (c >> 7) * 8;
      vv[i] = *(const ushort8v*)(Vp + (size_t)(j * 128 + key) * E + db);
    }
  };
  auto stageK = [&](int j, int buf) {
#pragma unroll
    for (int i = 0; i < 2; ++i) {
      int c = tid + 512 * i;
      int row = c >> 3, slot = c & 7;
      int gc = slot ^ (row & 7);
      async16(Kp + (size_t)(j * 128 + row) * E + gc * 8, &Kt[buf][c * 8]);
    }
  };
  auto scatV = [&](int buf) {
#pragma unroll
    for (int i = 0; i < 2; ++i) {
      int c = tid + 512 * i;
      int key = c & 127, db = (c >> 7) * 8;
#pragma unroll
      for (int jj = 0; jj < 8; ++jj) {
        int n = db + jj;
        int slot = (key >> 3) ^ (n & 15);
        Vt[buf][n * 128 + slot * 8 + (key & 7)] = vv[i][jj];
      }
    }
  };

  // softmax for one tile's 64-key chunk: mask (if diag), online max/sum, pack P -> bf16x4
  // sacc layout: q = li, key = h*64 + nt*16 + g*4 + r
  auto softmax_pf = [&](f32x4 (&sacc)[4], float& mi, float& ls, f32x4 (&oa)[4],
                        bool diag, int h, bf16x4 (&pf)[4]) {
    if (diag && h * 64 + 63 > wv * 16) { // chunk overlaps diagonal: mask key > q
#pragma unroll
      for (int nt = 0; nt < 4; ++nt)
#pragma unroll
        for (int r = 0; r < 4; ++r) {
          int keyg = h * 64 + nt * 16 + g * 4 + r;
          int qg = wv * 16 + li;
          sacc[nt][r] = (keyg > qg) ? -1e30f : sacc[nt][r];
        }
    }
    float mx = sacc[0][0];
#pragma unroll
    for (int nt = 0; nt < 4; ++nt)
#pragma unroll
      for (int r = 0; r < 4; ++r) mx = fmaxf(mx, sacc[nt][r]);
    mx = fmaxf(mx, __shfl_xor(mx, 16));
    mx = fmaxf(mx, __shfl_xor(mx, 32));
    float mnew = fmaxf(mi, mx);
    float alpha = __expf(mi - mnew);
    mi = mnew;

    float rs = 0.0f;
#pragma unroll
    for (int nt = 0; nt < 4; ++nt) {
      float p0 = __expf(sacc[nt][0] - mi);
      float p1 = __expf(sacc[nt][1] - mi);
      float p2 = __expf(sacc[nt][2] - mi);
      float p3 = __expf(sacc[nt][3] - mi);
      rs += (p0 + p1) + (p2 + p3);
      bf16x4 t;
      t[0] = (__bf16)p0; t[1] = (__bf16)p1; t[2] = (__bf16)p2; t[3] = (__bf16)p3;
      pf[nt] = t;
    }
    float s = rs;
    s += __shfl_xor(s, 16);
    s += __shfl_xor(s, 32);
    ls = ls * alpha + s;
#pragma unroll
    for (int dt = 0; dt < 4; ++dt) oa[dt] *= alpha;
  };

  // fused compute of both q-tiles over one staged 128-key tile
  auto compute2 = [&](bool doLo, bool diagH, bool diagL, int buf) {
#pragma unroll
    for (int h = 0; h < 2; ++h) {
      const bool skipTop = (h * 64 > wv * 16 + 15); // chunk above this wave's rows
      const bool aH = !(diagH && skipTop);
      const bool aL = doLo && !(diagL && skipTop);
      if (!aH && !aL) continue;

      // S^T = K Q^T for 64 keys: kf read once, used by both tiles
      f32x4 sH[4] = {}, sL[4] = {};
#pragma unroll
      for (int kk = 0; kk < 2; ++kk) {
        bf16x8 kf[4];
#pragma unroll
        for (int nt = 0; nt < 4; ++nt) {
          int key = h * 64 + nt * 16 + li;
          int slot = (kk * 4 + g) ^ (key & 7);
          kf[nt] = *(const bf16x8*)&Kt[buf][key * 64 + slot * 8];
        }
#pragma unroll
        for (int nt = 0; nt < 4; ++nt) {
          if (aH)
            sH[nt] = __builtin_amdgcn_mfma_f32_16x16x32_bf16(kf[nt], qfH[kk], sH[nt], 0, 0, 0);
          if (aL)
            sL[nt] = __builtin_amdgcn_mfma_f32_16x16x32_bf16(kf[nt], qfL[kk], sL[nt], 0, 0, 0);
        }
      }

      bf16x4 pfH[4], pfL[4];
      if (aH) softmax_pf(sH, miH, lsH, oaH, diagH, h, pfH);
      if (aL) softmax_pf(sL, miL, lsL, oaL, diagL, h, pfL);

      // O^T += V^T P^T via 16x16x16 MFMA: vf read once per (dt, c), P in-lane.
      // vf A-frag: lane holds V^T[d = dt*16+li][key = c*16 + g*4 .. +3]
#pragma unroll
      for (int dt = 0; dt < 4; ++dt) {
        bf16x4 vf[4];
#pragma unroll
        for (int c4 = 0; c4 < 4; ++c4) {
          int c = h * 4 + c4;
          int slot = (c * 2 + (g >> 1)) ^ li;
          vf[c4] = *(const bf16x4*)&Vt[buf][(dt * 16 + li) * 128 + slot * 8 + (g & 1) * 4];
        }
#pragma unroll
        for (int c4 = 0; c4 < 4; ++c4) {
          if (aH) oaH[dt] = mfma16(vf[c4], pfH[c4], oaH[dt]);
          if (aL) oaL[dt] = mfma16(vf[c4], pfL[c4], oaL[dt]);
        }
      }
    }
  };

  // prologue: stage tile 0 into buf 0
  loadV(0);
  stageK(0, 0);
  scatV(0);

  for (int j = 0; j <= qhi; ++j) {
    const int buf = j & 1;
    asm volatile("s_waitcnt vmcnt(0)" ::: "memory"); // K(j) async + any V loads drained
    __syncthreads();                                  // staging of tile j visible to all
    if (j < qhi) {
      loadV(j + 1);           // V global loads in flight across the compute phase
      stageK(j + 1, buf ^ 1); // async16 into the retired buffer
    }
    compute2(j <= qlo, j == qhi, j == qlo, buf);
    if (j < qhi) scatV(buf ^ 1); // transpose-scatter V(j+1); visible after next barrier
  }

  // epilogue: lane holds O^T col q=li, rows d=dt*16+g*4+r -> O[q][d] contiguous in d
#pragma unroll
  for (int t = 0; t < 2; ++t) {
    const int qt = t ? qhi : qlo;
    f32x4(&oa)[4] = t ? oaH : oaL;
    float ls = t ? lsH : lsL;
    float inv = 1.0f / ls;
    int row = qt * 128 + wv * 16 + li;
#pragma unroll
    for (int dt = 0; dt < 4; ++dt) {
      ushort4 w;
      w.x = f2bf(oa[dt][0] * inv);
      w.y = f2bf(oa[dt][1] * inv);
      w.z = f2bf(oa[dt][2] * inv);
      w.w = f2bf(oa[dt][3] * inv);
      *(ushort4*)(Op + (size_t)row * E + dt * 16 + g * 4) = w;
    }
  }
}

// ---------------- launch ----------------
extern "C" void kernel_launch(void* const* d_in, const int* in_sizes, int n_in,
                              void* d_out, int out_size, void* d_ws, size_t ws_size,
                              hipStream_t stream) {
  const float* q  = (const float*)d_in[0];
  const float* k  = (const float*)d_in[1];
  const float* v  = (const float*)d_in[2];
  const float* Wq = (const float*)d_in[3];
  const float* bq = (const float*)d_in[4];
  const float* Wk = (const float*)d_in[5];
  const float* bk = (const float*)d_in[6];
  const float* Wv = (const float*)d_in[7];
  const float* bv = (const float*)d_in[8];
  const float* Wo = (const float*)d_in[9];
  const float* bo = (const float*)d_in[10];

  unsigned short* Xq  = (unsigned short*)d_ws;
  unsigned short* Xk  = Xq + (size_t)MROWS * E;
  unsigned short* Xv  = Xk + (size_t)MROWS * E;
  unsigned short* Wqb = Xv + (size_t)MROWS * E;
  unsigned short* Wkb = Wqb + (size_t)E * E;
  unsigned short* Wvb = Wkb + (size_t)E * E;
  unsigned short* Wob = Wvb + (size_t)E * E;
  unsigned short* Qb  = Wob + (size_t)E * E;
  unsigned short* Kb  = Qb + (size_t)MROWS * E;
  unsigned short* Vb  = Kb + (size_t)MROWS * E;
  unsigned short* Og  = Xq; // Xq region is dead after the QKV GEMM

  CastArgs ca;
  ca.src[0] = q; ca.src[1] = k; ca.src[2] = v; ca.src[3] = nullptr;
  ca.dst[0] = Xq; ca.dst[1] = Xk; ca.dst[2] = Xv; ca.dst[3] = nullptr;
  ca.n = MROWS * E;
  cast_kernel<<<dim3(1024, 1, 3), 256, 0, stream>>>(ca);

  CastArgs cw;
  cw.src[0] = Wq; cw.src[1] = Wk; cw.src[2] = Wv; cw.src[3] = Wo;
  cw.dst[0] = Wqb; cw.dst[1] = Wkb; cw.dst[2] = Wvb; cw.dst[3] = Wob;
  cw.n = E * E;
  cast_kernel<<<dim3(256, 1, 4), 256, 0, stream>>>(cw);

  QkvArgs p;
  p.A[0] = Xq;  p.A[1] = Xk;  p.A[2] = Xv;
  p.W[0] = Wqb; p.W[1] = Wkb; p.W[2] = Wvb;
  p.bias[0] = bq; p.bias[1] = bk; p.bias[2] = bv;
  p.out[0] = Qb; p.out[1] = Kb; p.out[2] = Vb;
  p.scale[0] = 0.125f; p.scale[1] = 1.0f; p.scale[2] = 1.0f; // SCALE folded into Q
  gemm_qkv<<<dim3(64, 8, 3), 256, 0, stream>>>(p);

  flash_kernel<<<dim3(8, 64), 512, 0, stream>>>(Qb, Kb, Vb, Og);

  gemm_out_k<<<dim3(64, 8), 256, 0, stream>>>(Og, Wob, bo, (float*)d_out);
}

// Round 3
// 422.579 us; speedup vs baseline: 1.1378x; 1.1378x over previous
//
#include <hip/hip_runtime.h>

// Attention_72275709657473 — full MHA block on gfx950.
// Pipeline: cast(fp32->bf16) -> QKV proj GEMM (bf16 MFMA) -> causal flash attn -> out proj.
// Flash: TRANSPOSED formulation (S^T = K Q^T, O^T = V^T P^T), round-1 structure (unfused,
// fits 64 VGPRs -- round-2's hi/lo fusion spilled: +260MB scratch traffic) with round-2's
// verified in-lane PV:
//   * PV uses v_mfma_f32_16x16x16_bf16: its B-frag k-index (g*4+j) matches the QK C-layout
//     row index (g*4+r) exactly, so packed P feeds PV IN-LANE -- no ds_bpermute broadcasts.
//   * triangle pairing: block (p,bh) owns q-tiles {p, 15-p} (balanced grid, 512 blocks)
//   * double-buffered LDS (64KB, 2 blocks/CU), async16 K staging, reg-staged V transpose.
//   * 8 waves/block: wave owns 16 rows of hi tile + 16 rows of lo tile.
// ws layout: Xq/Xk/Xv bf16 (3x16MB) | Wq/Wk/Wv/Wo bf16 (4x2MB) | Q/K/V bf16 (3x16MB).
// Og (attn output, bf16) reuses the Xq region. Total ~104MB.

#define E 1024
#define HEADS 16
#define HD 64
#define SEQ 2048
#define BATCH 4
#define MROWS (BATCH * SEQ) /* 8192 */

typedef __bf16 bf16x8 __attribute__((ext_vector_type(8)));
typedef __bf16 bf16x4 __attribute__((ext_vector_type(4)));
typedef __bf16 bf16x2 __attribute__((ext_vector_type(2)));
typedef float f32x4 __attribute__((ext_vector_type(4)));
typedef short short4v __attribute__((ext_vector_type(4)));
typedef unsigned short ushort8v __attribute__((ext_vector_type(8)));

typedef __attribute__((address_space(1))) void gvoid;
typedef __attribute__((address_space(3))) void lvoid;

__device__ __forceinline__ void async16(const void* g, void* l) {
  __builtin_amdgcn_global_load_lds((gvoid*)g, (lvoid*)l, 16, 0, 0);
}

__device__ __forceinline__ unsigned short f2bf(float f) {
  union { float f; unsigned int u; } v;
  v.f = f;
  unsigned int r = v.u + 0x7FFFu + ((v.u >> 16) & 1u); // round-to-nearest-even
  return (unsigned short)(r >> 16);
}

__device__ __forceinline__ f32x4 mfma16(bf16x4 a, bf16x4 b, f32x4 c) {
  return __builtin_amdgcn_mfma_f32_16x16x16bf16_1k(
      __builtin_bit_cast(short4v, a), __builtin_bit_cast(short4v, b), c, 0, 0, 0);
}

__device__ __forceinline__ void store_out(unsigned short* p, float v) { *p = f2bf(v); }
__device__ __forceinline__ void store_out(float* p, float v) { *p = v; }

// ---------------- cast kernels ----------------
struct CastArgs {
  const float* src[4];
  unsigned short* dst[4];
  int n;
};

__global__ __launch_bounds__(256) void cast_kernel(CastArgs a) {
  const float* s = a.src[blockIdx.z];
  unsigned short* d = a.dst[blockIdx.z];
  const int n = a.n;
  const int stride = gridDim.x * blockDim.x * 4;
  for (int i = (blockIdx.x * blockDim.x + threadIdx.x) * 4; i < n; i += stride) {
    float4 v = *(const float4*)(s + i);
    ushort4 o;
    o.x = f2bf(v.x); o.y = f2bf(v.y); o.z = f2bf(v.z); o.w = f2bf(v.w);
    *(ushort4*)(d + i) = o;
  }
}

// ---------------- GEMM: C[M,N] = A[M,K] @ W[N,K]^T, epilogue (acc+bias)*scale ----------------
// 128x128 tile, BK=64, 256 threads = 4 waves in 2x2, each wave 64x64 (4x4 of 16x16x32 MFMA).
// LDS tiles row-major 128x64 bf16, XOR chunk swizzle: chunk c of row r at slot c^(r&7).
template <typename OutT>
__device__ __forceinline__ void gemm_body(const unsigned short* __restrict__ A,
                                          const unsigned short* __restrict__ W,
                                          const float* __restrict__ bias,
                                          OutT* __restrict__ out, float scale) {
  __shared__ unsigned short At[128 * 64];
  __shared__ unsigned short Wt[128 * 64];
  const int tid = threadIdx.x;
  const int lane = tid & 63;
  const int wv = tid >> 6;
  const int wm = wv & 1, wn = wv >> 1;
  const int li = lane & 15, g = lane >> 4;
  const int m0 = blockIdx.x * 128, n0 = blockIdx.y * 128;
  f32x4 acc[4][4] = {};

  for (int k0 = 0; k0 < E; k0 += 64) {
    __syncthreads();
#pragma unroll
    for (int i = 0; i < 4; ++i) {
      int c = tid + 256 * i;
      int row = c >> 3, slot = c & 7;
      int gc = slot ^ (row & 7);
      async16(A + (size_t)(m0 + row) * E + k0 + gc * 8, &At[c * 8]);
      async16(W + (size_t)(n0 + row) * E + k0 + gc * 8, &Wt[c * 8]);
    }
    asm volatile("s_waitcnt vmcnt(0)" ::: "memory");
    __syncthreads();
#pragma unroll
    for (int kk = 0; kk < 2; ++kk) {
      bf16x8 af[4], bfr[4];
#pragma unroll
      for (int mt = 0; mt < 4; ++mt) {
        int r = wm * 64 + mt * 16 + li;
        int slot = (kk * 4 + g) ^ (r & 7);
        af[mt] = *(const bf16x8*)&At[r * 64 + slot * 8];
      }
#pragma unroll
      for (int nt = 0; nt < 4; ++nt) {
        int r = wn * 64 + nt * 16 + li;
        int slot = (kk * 4 + g) ^ (r & 7);
        bfr[nt] = *(const bf16x8*)&Wt[r * 64 + slot * 8];
      }
#pragma unroll
      for (int mt = 0; mt < 4; ++mt)
#pragma unroll
        for (int nt = 0; nt < 4; ++nt)
          acc[mt][nt] =
              __builtin_amdgcn_mfma_f32_16x16x32_bf16(af[mt], bfr[nt], acc[mt][nt], 0, 0, 0);
    }
  }

#pragma unroll
  for (int nt = 0; nt < 4; ++nt) {
    int col = n0 + wn * 64 + nt * 16 + li;
    float bv = bias[col];
#pragma unroll
    for (int mt = 0; mt < 4; ++mt) {
#pragma unroll
      for (int r = 0; r < 4; ++r) {
        int row = m0 + wm * 64 + mt * 16 + g * 4 + r;
        store_out(&out[(size_t)row * E + col], (acc[mt][nt][r] + bv) * scale);
      }
    }
  }
}

struct QkvArgs {
  const unsigned short* A[3];
  const unsigned short* W[3];
  const float* bias[3];
  unsigned short* out[3];
  float scale[3];
};

__global__ __launch_bounds__(256) void gemm_qkv(QkvArgs p) {
  const int z = blockIdx.z;
  gemm_body<unsigned short>(p.A[z], p.W[z], p.bias[z], p.out[z], p.scale[z]);
}

__global__ __launch_bounds__(256) void gemm_out_k(const unsigned short* __restrict__ A,
                                                  const unsigned short* __restrict__ W,
                                                  const float* __restrict__ bias,
                                                  float* __restrict__ out) {
  gemm_body<float>(A, W, bias, out, 1.0f);
}

// ---------------- causal flash attention (transposed, paired, double-buffered) ----------------
// grid (8 pairs, 64 b*h), 512 threads = 8 waves; wave w owns rows [16w,16w+16) of BOTH
// q-tiles {p, 15-p}. Per staged 128-key tile j (0..15-p): compute hi tile always, lo tile
// when j <= p. 64-key chunks keep sacc small. One barrier per iter; prefetch j+1.
// QK = 16x16x32 MFMA; PV = 16x16x16 MFMA with P in-lane (no cross-lane shuffles).
__global__ __launch_bounds__(512, 4) void flash_kernel(const unsigned short* __restrict__ Qb,
                                                       const unsigned short* __restrict__ Kb,
                                                       const unsigned short* __restrict__ Vb,
                                                       unsigned short* __restrict__ Ob) {
  __shared__ unsigned short Kt[2][128 * 64];
  __shared__ unsigned short Vt[2][64 * 128];
  const int p = blockIdx.x;  // 0..7
  const int bh = blockIdx.y;
  const int b = bh >> 4, h16 = bh & 15;
  const size_t base = (size_t)b * SEQ * E + (size_t)h16 * HD;
  const unsigned short* Qp = Qb + base;
  const unsigned short* Kp = Kb + base;
  const unsigned short* Vp = Vb + base;
  unsigned short* Op = Ob + base;
  const int tid = threadIdx.x, lane = tid & 63, wv = tid >> 6; // wv in 0..7
  const int li = lane & 15, g = lane >> 4;
  const int qlo = p, qhi = 15 - p;

  // Q fragments (B-operand layout): lane holds Q[q = li][d = kk*32 + g*8 .. +7]
  bf16x8 qfL[2], qfH[2];
#pragma unroll
  for (int kk = 0; kk < 2; ++kk) {
    int rl = qlo * 128 + wv * 16 + li;
    int rh = qhi * 128 + wv * 16 + li;
    qfL[kk] = *(const bf16x8*)(Qp + (size_t)rl * E + kk * 32 + g * 8);
    qfH[kk] = *(const bf16x8*)(Qp + (size_t)rh * E + kk * 32 + g * 8);
  }

  f32x4 oaL[4] = {}, oaH[4] = {}; // O^T C-layout: col=q=li, row=d=g*4+r
  float miL = -1e30f, lsL = 0.0f;
  float miH = -1e30f, lsH = 0.0f;

  ushort8v vv[2]; // V prefetch registers

  auto loadV = [&](int j) {
#pragma unroll
    for (int i = 0; i < 2; ++i) {
      int c = tid + 512 * i;
      int key = c & 127, db = (c >> 7) * 8;
      vv[i] = *(const ushort8v*)(Vp + (size_t)(j * 128 + key) * E + db);
    }
  };
  auto stageK = [&](int j, int buf) {
#pragma unroll
    for (int i = 0; i < 2; ++i) {
      int c = tid + 512 * i;
      int row = c >> 3, slot = c & 7;
      int gc = slot ^ (row & 7);
      async16(Kp + (size_t)(j * 128 + row) * E + gc * 8, &Kt[buf][c * 8]);
    }
  };
  auto scatV = [&](int buf) {
#pragma unroll
    for (int i = 0; i < 2; ++i) {
      int c = tid + 512 * i;
      int key = c & 127, db = (c >> 7) * 8;
#pragma unroll
      for (int jj = 0; jj < 8; ++jj) {
        int n = db + jj;
        int slot = (key >> 3) ^ (n & 15);
        Vt[buf][n * 128 + slot * 8 + (key & 7)] = vv[i][jj];
      }
    }
  };

  auto compute = [&](const bf16x8 (&qf)[2], float& mi, float& ls,
                     f32x4 (&oa)[4], bool diag, int buf) {
#pragma unroll
    for (int h = 0; h < 2; ++h) {
      // wave-uniform skip: chunk entirely above the diagonal for this wave's rows
      if (diag && h * 64 > wv * 16 + 15) continue;

      // S^T = K Q^T for 64 keys: 4 key-tiles x 1 q-tile
      f32x4 sacc[4] = {};
#pragma unroll
      for (int kk = 0; kk < 2; ++kk) {
        bf16x8 kf[4];
#pragma unroll
        for (int nt = 0; nt < 4; ++nt) {
          int key = h * 64 + nt * 16 + li;
          int slot = (kk * 4 + g) ^ (key & 7);
          kf[nt] = *(const bf16x8*)&Kt[buf][key * 64 + slot * 8];
        }
#pragma unroll
        for (int nt = 0; nt < 4; ++nt)
          sacc[nt] =
              __builtin_amdgcn_mfma_f32_16x16x32_bf16(kf[nt], qf[kk], sacc[nt], 0, 0, 0);
      }

      if (diag && h * 64 + 63 > wv * 16) { // chunk overlaps diagonal: mask key > q
#pragma unroll
        for (int nt = 0; nt < 4; ++nt)
#pragma unroll
          for (int r = 0; r < 4; ++r) {
            int keyg = h * 64 + nt * 16 + g * 4 + r;
            int qg = wv * 16 + li;
            sacc[nt][r] = (keyg > qg) ? -1e30f : sacc[nt][r];
          }
      }

      // online softmax per q (C-layout col): in-lane 16 keys, then shfl_xor 16/32
      float mx = sacc[0][0];
#pragma unroll
      for (int nt = 0; nt < 4; ++nt)
#pragma unroll
        for (int r = 0; r < 4; ++r) mx = fmaxf(mx, sacc[nt][r]);
      mx = fmaxf(mx, __shfl_xor(mx, 16));
      mx = fmaxf(mx, __shfl_xor(mx, 32));
      float mnew = fmaxf(mi, mx);
      float alpha = __expf(mi - mnew);
      mi = mnew;

      bf16x4 pf[4]; // packed bf16 P^T, in-lane B-frag for 16x16x16 PV MFMA
      float rs = 0.0f;
#pragma unroll
      for (int nt = 0; nt < 4; ++nt) {
        float p0 = __expf(sacc[nt][0] - mi);
        float p1 = __expf(sacc[nt][1] - mi);
        float p2 = __expf(sacc[nt][2] - mi);
        float p3 = __expf(sacc[nt][3] - mi);
        rs += (p0 + p1) + (p2 + p3);
        bf16x4 t;
        t[0] = (__bf16)p0; t[1] = (__bf16)p1; t[2] = (__bf16)p2; t[3] = (__bf16)p3;
        pf[nt] = t;
      }
      {
        float s = rs;
        s += __shfl_xor(s, 16);
        s += __shfl_xor(s, 32);
        ls = ls * alpha + s;
#pragma unroll
        for (int dt = 0; dt < 4; ++dt) oa[dt] *= alpha;
      }

      // O^T += V^T P^T via 16x16x16 MFMA: P in-lane.
      // vf A-frag: lane holds V^T[d = dt*16+li][key = c*16 + g*4 .. +3]
#pragma unroll
      for (int dt = 0; dt < 4; ++dt) {
        bf16x4 vf[4];
#pragma unroll
        for (int c4 = 0; c4 < 4; ++c4) {
          int c = h * 4 + c4;
          int slot = (c * 2 + (g >> 1)) ^ li;
          vf[c4] = *(const bf16x4*)&Vt[buf][(dt * 16 + li) * 128 + slot * 8 + (g & 1) * 4];
        }
#pragma unroll
        for (int c4 = 0; c4 < 4; ++c4)
          oa[dt] = mfma16(vf[c4], pf[c4], oa[dt]);
      }
    }
  };

  // prologue: stage tile 0 into buf 0
  loadV(0);
  stageK(0, 0);
  scatV(0);

  for (int j = 0; j <= qhi; ++j) {
    const int buf = j & 1;
    asm volatile("s_waitcnt vmcnt(0)" ::: "memory"); // K(j) async + any V loads drained
    __syncthreads();                                  // staging of tile j visible to all
    if (j < qhi) {
      loadV(j + 1);           // V global loads in flight across the compute phase
      stageK(j + 1, buf ^ 1); // async16 into the retired buffer
    }
    compute(qfH, miH, lsH, oaH, j == qhi, buf);
    if (j <= qlo) compute(qfL, miL, lsL, oaL, j == qlo, buf);
    if (j < qhi) scatV(buf ^ 1); // transpose-scatter V(j+1); visible after next barrier
  }

  // epilogue: lane holds O^T col q=li, rows d=dt*16+g*4+r -> O[q][d] contiguous in d
#pragma unroll
  for (int t = 0; t < 2; ++t) {
    const int qt = t ? qhi : qlo;
    f32x4(&oa)[4] = t ? oaH : oaL;
    float ls = t ? lsH : lsL;
    float inv = 1.0f / ls;
    int row = qt * 128 + wv * 16 + li;
#pragma unroll
    for (int dt = 0; dt < 4; ++dt) {
      ushort4 w;
      w.x = f2bf(oa[dt][0] * inv);
      w.y = f2bf(oa[dt][1] * inv);
      w.z = f2bf(oa[dt][2] * inv);
      w.w = f2bf(oa[dt][3] * inv);
      *(ushort4*)(Op + (size_t)row * E + dt * 16 + g * 4) = w;
    }
  }
}

// ---------------- launch ----------------
extern "C" void kernel_launch(void* const* d_in, const int* in_sizes, int n_in,
                              void* d_out, int out_size, void* d_ws, size_t ws_size,
                              hipStream_t stream) {
  const float* q  = (const float*)d_in[0];
  const float* k  = (const float*)d_in[1];
  const float* v  = (const float*)d_in[2];
  const float* Wq = (const float*)d_in[3];
  const float* bq = (const float*)d_in[4];
  const float* Wk = (const float*)d_in[5];
  const float* bk = (const float*)d_in[6];
  const float* Wv = (const float*)d_in[7];
  const float* bv = (const float*)d_in[8];
  const float* Wo = (const float*)d_in[9];
  const float* bo = (const float*)d_in[10];

  unsigned short* Xq  = (unsigned short*)d_ws;
  unsigned short* Xk  = Xq + (size_t)MROWS * E;
  unsigned short* Xv  = Xk + (size_t)MROWS * E;
  unsigned short* Wqb = Xv + (size_t)MROWS * E;
  unsigned short* Wkb = Wqb + (size_t)E * E;
  unsigned short* Wvb = Wkb + (size_t)E * E;
  unsigned short* Wob = Wvb + (size_t)E * E;
  unsigned short* Qb  = Wob + (size_t)E * E;
  unsigned short* Kb  = Qb + (size_t)MROWS * E;
  unsigned short* Vb  = Kb + (size_t)MROWS * E;
  unsigned short* Og  = Xq; // Xq region is dead after the QKV GEMM

  CastArgs ca;
  ca.src[0] = q; ca.src[1] = k; ca.src[2] = v; ca.src[3] = nullptr;
  ca.dst[0] = Xq; ca.dst[1] = Xk; ca.dst[2] = Xv; ca.dst[3] = nullptr;
  ca.n = MROWS * E;
  cast_kernel<<<dim3(1024, 1, 3), 256, 0, stream>>>(ca);

  CastArgs cw;
  cw.src[0] = Wq; cw.src[1] = Wk; cw.src[2] = Wv; cw.src[3] = Wo;
  cw.dst[0] = Wqb; cw.dst[1] = Wkb; cw.dst[2] = Wvb; cw.dst[3] = Wob;
  cw.n = E * E;
  cast_kernel<<<dim3(256, 1, 4), 256, 0, stream>>>(cw);

  QkvArgs p;
  p.A[0] = Xq;  p.A[1] = Xk;  p.A[2] = Xv;
  p.W[0] = Wqb; p.W[1] = Wkb; p.W[2] = Wvb;
  p.bias[0] = bq; p.bias[1] = bk; p.bias[2] = bv;
  p.out[0] = Qb; p.out[1] = Kb; p.out[2] = Vb;
  p.scale[0] = 0.125f; p.scale[1] = 1.0f; p.scale[2] = 1.0f; // SCALE folded into Q
  gemm_qkv<<<dim3(64, 8, 3), 256, 0, stream>>>(p);

  flash_kernel<<<dim3(8, 64), 512, 0, stream>>>(Qb, Kb, Vb, Og);

  gemm_out_k<<<dim3(64, 8), 256, 0, stream>>>(Og, Wob, bo, (float*)d_out);
}

// Round 4
// 398.191 us; speedup vs baseline: 1.2075x; 1.0612x over previous
//
#include <hip/hip_runtime.h>

// Attention_72275709657473 — full MHA block on gfx950.
// Pipeline: cast(fp32->bf16) -> QKV proj GEMM (bf16 MFMA) -> causal flash attn -> out proj.
// Flash: TRANSPOSED formulation (S^T = K Q^T, O^T = V^T P^T), fused hi/lo (R2 structure,
// correctness-verified) with the VGPR cap fixed: __launch_bounds__(512, 2) -> 128-reg cap
// (R2 used (512,4) which hipcc treats CUDA-style as 4 blocks/CU -> 8 waves/EU -> 64-reg cap
// -> 260MB of scratch spill traffic). LDS 64KB still caps at 2 blocks/CU, so occupancy is
// unchanged (4 waves/SIMD) while the fused working set (~110 regs) now fits.
//   * PV uses v_mfma_f32_16x16x16_bf16: B-frag k-index (g*4+j) == QK C-layout row index,
//     so packed P feeds PV IN-LANE (no shuffles). Verified in R2/R3.
//   * hi/lo q-tile computes fused per chunk: Kt/Vt fragments read ONCE, serve both tiles;
//     two independent softmax chains per wave for the scheduler to interleave.
//   * tree max/sum (serial depth 15 -> 4), exact skip-rescale when __all(mx<=mi),
//     s_setprio(1) around MFMA clusters.
//   * triangle pairing: block (p,bh) owns q-tiles {p, 15-p} (balanced, 512 blocks);
//     double-buffered LDS, async16 K staging, reg-staged V transpose-scatter.
// ws layout: Xq/Xk/Xv bf16 (3x16MB) | Wq/Wk/Wv/Wo bf16 (4x2MB) | Q/K/V bf16 (3x16MB).
// Og (attn output, bf16) reuses the Xq region. Total ~104MB.

#define E 1024
#define HEADS 16
#define HD 64
#define SEQ 2048
#define BATCH 4
#define MROWS (BATCH * SEQ) /* 8192 */

typedef __bf16 bf16x8 __attribute__((ext_vector_type(8)));
typedef __bf16 bf16x4 __attribute__((ext_vector_type(4)));
typedef __bf16 bf16x2 __attribute__((ext_vector_type(2)));
typedef float f32x4 __attribute__((ext_vector_type(4)));
typedef short short4v __attribute__((ext_vector_type(4)));
typedef unsigned short ushort8v __attribute__((ext_vector_type(8)));

typedef __attribute__((address_space(1))) void gvoid;
typedef __attribute__((address_space(3))) void lvoid;

__device__ __forceinline__ void async16(const void* g, void* l) {
  __builtin_amdgcn_global_load_lds((gvoid*)g, (lvoid*)l, 16, 0, 0);
}

__device__ __forceinline__ unsigned short f2bf(float f) {
  union { float f; unsigned int u; } v;
  v.f = f;
  unsigned int r = v.u + 0x7FFFu + ((v.u >> 16) & 1u); // round-to-nearest-even
  return (unsigned short)(r >> 16);
}

__device__ __forceinline__ f32x4 mfma16(bf16x4 a, bf16x4 b, f32x4 c) {
  return __builtin_amdgcn_mfma_f32_16x16x16bf16_1k(
      __builtin_bit_cast(short4v, a), __builtin_bit_cast(short4v, b), c, 0, 0, 0);
}

__device__ __forceinline__ void store_out(unsigned short* p, float v) { *p = f2bf(v); }
__device__ __forceinline__ void store_out(float* p, float v) { *p = v; }

// ---------------- cast kernels ----------------
struct CastArgs {
  const float* src[4];
  unsigned short* dst[4];
  int n;
};

__global__ __launch_bounds__(256) void cast_kernel(CastArgs a) {
  const float* s = a.src[blockIdx.z];
  unsigned short* d = a.dst[blockIdx.z];
  const int n = a.n;
  const int stride = gridDim.x * blockDim.x * 4;
  for (int i = (blockIdx.x * blockDim.x + threadIdx.x) * 4; i < n; i += stride) {
    float4 v = *(const float4*)(s + i);
    ushort4 o;
    o.x = f2bf(v.x); o.y = f2bf(v.y); o.z = f2bf(v.z); o.w = f2bf(v.w);
    *(ushort4*)(d + i) = o;
  }
}

// ---------------- GEMM: C[M,N] = A[M,K] @ W[N,K]^T, epilogue (acc+bias)*scale ----------------
// 128x128 tile, BK=64, 256 threads = 4 waves in 2x2, each wave 64x64 (4x4 of 16x16x32 MFMA).
// LDS tiles row-major 128x64 bf16, XOR chunk swizzle: chunk c of row r at slot c^(r&7).
template <typename OutT>
__device__ __forceinline__ void gemm_body(const unsigned short* __restrict__ A,
                                          const unsigned short* __restrict__ W,
                                          const float* __restrict__ bias,
                                          OutT* __restrict__ out, float scale) {
  __shared__ unsigned short At[128 * 64];
  __shared__ unsigned short Wt[128 * 64];
  const int tid = threadIdx.x;
  const int lane = tid & 63;
  const int wv = tid >> 6;
  const int wm = wv & 1, wn = wv >> 1;
  const int li = lane & 15, g = lane >> 4;
  const int m0 = blockIdx.x * 128, n0 = blockIdx.y * 128;
  f32x4 acc[4][4] = {};

  for (int k0 = 0; k0 < E; k0 += 64) {
    __syncthreads();
#pragma unroll
    for (int i = 0; i < 4; ++i) {
      int c = tid + 256 * i;
      int row = c >> 3, slot = c & 7;
      int gc = slot ^ (row & 7);
      async16(A + (size_t)(m0 + row) * E + k0 + gc * 8, &At[c * 8]);
      async16(W + (size_t)(n0 + row) * E + k0 + gc * 8, &Wt[c * 8]);
    }
    asm volatile("s_waitcnt vmcnt(0)" ::: "memory");
    __syncthreads();
#pragma unroll
    for (int kk = 0; kk < 2; ++kk) {
      bf16x8 af[4], bfr[4];
#pragma unroll
      for (int mt = 0; mt < 4; ++mt) {
        int r = wm * 64 + mt * 16 + li;
        int slot = (kk * 4 + g) ^ (r & 7);
        af[mt] = *(const bf16x8*)&At[r * 64 + slot * 8];
      }
#pragma unroll
      for (int nt = 0; nt < 4; ++nt) {
        int r = wn * 64 + nt * 16 + li;
        int slot = (kk * 4 + g) ^ (r & 7);
        bfr[nt] = *(const bf16x8*)&Wt[r * 64 + slot * 8];
      }
#pragma unroll
      for (int mt = 0; mt < 4; ++mt)
#pragma unroll
        for (int nt = 0; nt < 4; ++nt)
          acc[mt][nt] =
              __builtin_amdgcn_mfma_f32_16x16x32_bf16(af[mt], bfr[nt], acc[mt][nt], 0, 0, 0);
    }
  }

#pragma unroll
  for (int nt = 0; nt < 4; ++nt) {
    int col = n0 + wn * 64 + nt * 16 + li;
    float bv = bias[col];
#pragma unroll
    for (int mt = 0; mt < 4; ++mt) {
#pragma unroll
      for (int r = 0; r < 4; ++r) {
        int row = m0 + wm * 64 + mt * 16 + g * 4 + r;
        store_out(&out[(size_t)row * E + col], (acc[mt][nt][r] + bv) * scale);
      }
    }
  }
}

struct QkvArgs {
  const unsigned short* A[3];
  const unsigned short* W[3];
  const float* bias[3];
  unsigned short* out[3];
  float scale[3];
};

__global__ __launch_bounds__(256) void gemm_qkv(QkvArgs p) {
  const int z = blockIdx.z;
  gemm_body<unsigned short>(p.A[z], p.W[z], p.bias[z], p.out[z], p.scale[z]);
}

__global__ __launch_bounds__(256) void gemm_out_k(const unsigned short* __restrict__ A,
                                                  const unsigned short* __restrict__ W,
                                                  const float* __restrict__ bias,
                                                  float* __restrict__ out) {
  gemm_body<float>(A, W, bias, out, 1.0f);
}

// ---------------- causal flash attention (transposed, paired, fused hi/lo, in-lane PV) ----
// grid (8 pairs, 64 b*h), 512 threads = 8 waves; wave w owns rows [16w,16w+16) of BOTH
// q-tiles {p, 15-p}. Per staged 128-key tile j (0..15-p), per 64-key chunk: Kt/Vt fragments
// read once and shared by hi (always) and lo (j<=p) tiles. QK = 16x16x32 MFMA; PV =
// 16x16x16 MFMA whose B-frag takes packed P straight from the QK C-layout (no shuffles).
__global__ __launch_bounds__(512, 2) void flash_kernel(const unsigned short* __restrict__ Qb,
                                                       const unsigned short* __restrict__ Kb,
                                                       const unsigned short* __restrict__ Vb,
                                                       unsigned short* __restrict__ Ob) {
  __shared__ unsigned short Kt[2][128 * 64];
  __shared__ unsigned short Vt[2][64 * 128];
  const int p = blockIdx.x;  // 0..7
  const int bh = blockIdx.y;
  const int b = bh >> 4, h16 = bh & 15;
  const size_t base = (size_t)b * SEQ * E + (size_t)h16 * HD;
  const unsigned short* Qp = Qb + base;
  const unsigned short* Kp = Kb + base;
  const unsigned short* Vp = Vb + base;
  unsigned short* Op = Ob + base;
  const int tid = threadIdx.x, lane = tid & 63, wv = tid >> 6; // wv in 0..7
  const int li = lane & 15, g = lane >> 4;
  const int qlo = p, qhi = 15 - p;

  // Q fragments (B-operand layout): lane holds Q[q = li][d = kk*32 + g*8 .. +7]
  bf16x8 qfL[2], qfH[2];
#pragma unroll
  for (int kk = 0; kk < 2; ++kk) {
    int rl = qlo * 128 + wv * 16 + li;
    int rh = qhi * 128 + wv * 16 + li;
    qfL[kk] = *(const bf16x8*)(Qp + (size_t)rl * E + kk * 32 + g * 8);
    qfH[kk] = *(const bf16x8*)(Qp + (size_t)rh * E + kk * 32 + g * 8);
  }

  f32x4 oaL[4] = {}, oaH[4] = {}; // O^T C-layout: col=q=li, row=d=g*4+r
  float miL = -1e30f, lsL = 0.0f;
  float miH = -1e30f, lsH = 0.0f;

  ushort8v vv[2]; // V prefetch registers

  auto loadV = [&](int j) {
#pragma unroll
    for (int i = 0; i < 2; ++i) {
      int c = tid + 512 * i;
      int key = c & 127, db = (c >> 7) * 8;
      vv[i] = *(const ushort8v*)(Vp + (size_t)(j * 128 + key) * E + db);
    }
  };
  auto stageK = [&](int j, int buf) {
#pragma unroll
    for (int i = 0; i < 2; ++i) {
      int c = tid + 512 * i;
      int row = c >> 3, slot = c & 7;
      int gc = slot ^ (row & 7);
      async16(Kp + (size_t)(j * 128 + row) * E + gc * 8, &Kt[buf][c * 8]);
    }
  };
  auto scatV = [&](int buf) {
#pragma unroll
    for (int i = 0; i < 2; ++i) {
      int c = tid + 512 * i;
      int key = c & 127, db = (c >> 7) * 8;
#pragma unroll
      for (int jj = 0; jj < 8; ++jj) {
        int n = db + jj;
        int slot = (key >> 3) ^ (n & 15);
        Vt[buf][n * 128 + slot * 8 + (key & 7)] = vv[i][jj];
      }
    }
  };

  // softmax for one tile's 64-key chunk: mask (if diag), tree max, exact skip-rescale,
  // exp + pack P -> bf16x4, tree sum. sacc layout: q = li, key = h*64 + nt*16 + g*4 + r
  auto softmax_pf = [&](f32x4 (&sacc)[4], float& mi, float& ls, f32x4 (&oa)[4],
                        bool diag, int h, bf16x4 (&pf)[4]) {
    if (diag && h * 64 + 63 > wv * 16) { // chunk overlaps diagonal: mask key > q
#pragma unroll
      for (int nt = 0; nt < 4; ++nt)
#pragma unroll
        for (int r = 0; r < 4; ++r) {
          int keyg = h * 64 + nt * 16 + g * 4 + r;
          int qg = wv * 16 + li;
          sacc[nt][r] = (keyg > qg) ? -1e30f : sacc[nt][r];
        }
    }
    // tree max (depth 4 instead of serial 15)
    float m4[4];
#pragma unroll
    for (int nt = 0; nt < 4; ++nt)
      m4[nt] = fmaxf(fmaxf(sacc[nt][0], sacc[nt][1]), fmaxf(sacc[nt][2], sacc[nt][3]));
    float mx = fmaxf(fmaxf(m4[0], m4[1]), fmaxf(m4[2], m4[3]));
    mx = fmaxf(mx, __shfl_xor(mx, 16));
    mx = fmaxf(mx, __shfl_xor(mx, 32));
    float mnew = fmaxf(mi, mx);
    if (!__all(mx <= mi)) { // exact: skipped only when alpha would be exp(0)=1
      float alpha = __expf(mi - mnew);
      ls *= alpha;
#pragma unroll
      for (int dt = 0; dt < 4; ++dt) oa[dt] *= alpha;
    }
    mi = mnew;

    float rs4[4];
#pragma unroll
    for (int nt = 0; nt < 4; ++nt) {
      float p0 = __expf(sacc[nt][0] - mi);
      float p1 = __expf(sacc[nt][1] - mi);
      float p2 = __expf(sacc[nt][2] - mi);
      float p3 = __expf(sacc[nt][3] - mi);
      rs4[nt] = (p0 + p1) + (p2 + p3);
      bf16x4 t;
      t[0] = (__bf16)p0; t[1] = (__bf16)p1; t[2] = (__bf16)p2; t[3] = (__bf16)p3;
      pf[nt] = t;
    }
    float s = (rs4[0] + rs4[1]) + (rs4[2] + rs4[3]);
    s += __shfl_xor(s, 16);
    s += __shfl_xor(s, 32);
    ls += s;
  };

  // fused compute of both q-tiles over one staged 128-key tile
  auto compute2 = [&](bool doLo, bool diagH, bool diagL, int buf) {
#pragma unroll
    for (int h = 0; h < 2; ++h) {
      const bool skipTop = (h * 64 > wv * 16 + 15); // chunk above this wave's rows
      const bool aH = !(diagH && skipTop);
      const bool aL = doLo && !(diagL && skipTop);
      if (!aH && !aL) continue;

      // S^T = K Q^T for 64 keys: kf read once, used by both tiles
      f32x4 sH[4] = {}, sL[4] = {};
#pragma unroll
      for (int kk = 0; kk < 2; ++kk) {
        bf16x8 kf[4];
#pragma unroll
        for (int nt = 0; nt < 4; ++nt) {
          int key = h * 64 + nt * 16 + li;
          int slot = (kk * 4 + g) ^ (key & 7);
          kf[nt] = *(const bf16x8*)&Kt[buf][key * 64 + slot * 8];
        }
        __builtin_amdgcn_s_setprio(1);
#pragma unroll
        for (int nt = 0; nt < 4; ++nt) {
          if (aH)
            sH[nt] = __builtin_amdgcn_mfma_f32_16x16x32_bf16(kf[nt], qfH[kk], sH[nt], 0, 0, 0);
          if (aL)
            sL[nt] = __builtin_amdgcn_mfma_f32_16x16x32_bf16(kf[nt], qfL[kk], sL[nt], 0, 0, 0);
        }
        __builtin_amdgcn_s_setprio(0);
      }

      bf16x4 pfH[4], pfL[4];
      if (aH) softmax_pf(sH, miH, lsH, oaH, diagH, h, pfH);
      if (aL) softmax_pf(sL, miL, lsL, oaL, diagL, h, pfL);

      // O^T += V^T P^T via 16x16x16 MFMA: vf read once per (dt, c), P in-lane.
      // vf A-frag: lane holds V^T[d = dt*16+li][key = c*16 + g*4 .. +3]
#pragma unroll
      for (int dt = 0; dt < 4; ++dt) {
        bf16x4 vf[4];
#pragma unroll
        for (int c4 = 0; c4 < 4; ++c4) {
          int c = h * 4 + c4;
          int slot = (c * 2 + (g >> 1)) ^ li;
          vf[c4] = *(const bf16x4*)&Vt[buf][(dt * 16 + li) * 128 + slot * 8 + (g & 1) * 4];
        }
        __builtin_amdgcn_s_setprio(1);
#pragma unroll
        for (int c4 = 0; c4 < 4; ++c4) {
          if (aH) oaH[dt] = mfma16(vf[c4], pfH[c4], oaH[dt]);
          if (aL) oaL[dt] = mfma16(vf[c4], pfL[c4], oaL[dt]);
        }
        __builtin_amdgcn_s_setprio(0);
      }
    }
  };

  // prologue: stage tile 0 into buf 0
  loadV(0);
  stageK(0, 0);
  scatV(0);

  for (int j = 0; j <= qhi; ++j) {
    const int buf = j & 1;
    asm volatile("s_waitcnt vmcnt(0)" ::: "memory"); // K(j) async + any V loads drained
    __syncthreads();                                  // staging of tile j visible to all
    if (j < qhi) {
      loadV(j + 1);           // V global loads in flight across the compute phase
      stageK(j + 1, buf ^ 1); // async16 into the retired buffer
    }
    compute2(j <= qlo, j == qhi, j == qlo, buf);
    if (j < qhi) scatV(buf ^ 1); // transpose-scatter V(j+1); visible after next barrier
  }

  // epilogue: lane holds O^T col q=li, rows d=dt*16+g*4+r -> O[q][d] contiguous in d
#pragma unroll
  for (int t = 0; t < 2; ++t) {
    const int qt = t ? qhi : qlo;
    f32x4(&oa)[4] = t ? oaH : oaL;
    float ls = t ? lsH : lsL;
    float inv = 1.0f / ls;
    int row = qt * 128 + wv * 16 + li;
#pragma unroll
    for (int dt = 0; dt < 4; ++dt) {
      ushort4 w;
      w.x = f2bf(oa[dt][0] * inv);
      w.y = f2bf(oa[dt][1] * inv);
      w.z = f2bf(oa[dt][2] * inv);
      w.w = f2bf(oa[dt][3] * inv);
      *(ushort4*)(Op + (size_t)row * E + dt * 16 + g * 4) = w;
    }
  }
}

// ---------------- launch ----------------
extern "C" void kernel_launch(void* const* d_in, const int* in_sizes, int n_in,
                              void* d_out, int out_size, void* d_ws, size_t ws_size,
                              hipStream_t stream) {
  const float* q  = (const float*)d_in[0];
  const float* k  = (const float*)d_in[1];
  const float* v  = (const float*)d_in[2];
  const float* Wq = (const float*)d_in[3];
  const float* bq = (const float*)d_in[4];
  const float* Wk = (const float*)d_in[5];
  const float* bk = (const float*)d_in[6];
  const float* Wv = (const float*)d_in[7];
  const float* bv = (const float*)d_in[8];
  const float* Wo = (const float*)d_in[9];
  const float* bo = (const float*)d_in[10];

  unsigned short* Xq  = (unsigned short*)d_ws;
  unsigned short* Xk  = Xq + (size_t)MROWS * E;
  unsigned short* Xv  = Xk + (size_t)MROWS * E;
  unsigned short* Wqb = Xv + (size_t)MROWS * E;
  unsigned short* Wkb = Wqb + (size_t)E * E;
  unsigned short* Wvb = Wkb + (size_t)E * E;
  unsigned short* Wob = Wvb + (size_t)E * E;
  unsigned short* Qb  = Wob + (size_t)E * E;
  unsigned short* Kb  = Qb + (size_t)MROWS * E;
  unsigned short* Vb  = Kb + (size_t)MROWS * E;
  unsigned short* Og  = Xq; // Xq region is dead after the QKV GEMM

  CastArgs ca;
  ca.src[0] = q; ca.src[1] = k; ca.src[2] = v; ca.src[3] = nullptr;
  ca.dst[0] = Xq; ca.dst[1] = Xk; ca.dst[2] = Xv; ca.dst[3] = nullptr;
  ca.n = MROWS * E;
  cast_kernel<<<dim3(1024, 1, 3), 256, 0, stream>>>(ca);

  CastArgs cw;
  cw.src[0] = Wq; cw.src[1] = Wk; cw.src[2] = Wv; cw.src[3] = Wo;
  cw.dst[0] = Wqb; cw.dst[1] = Wkb; cw.dst[2] = Wvb; cw.dst[3] = Wob;
  cw.n = E * E;
  cast_kernel<<<dim3(256, 1, 4), 256, 0, stream>>>(cw);

  QkvArgs p;
  p.A[0] = Xq;  p.A[1] = Xk;  p.A[2] = Xv;
  p.W[0] = Wqb; p.W[1] = Wkb; p.W[2] = Wvb;
  p.bias[0] = bq; p.bias[1] = bk; p.bias[2] = bv;
  p.out[0] = Qb; p.out[1] = Kb; p.out[2] = Vb;
  p.scale[0] = 0.125f; p.scale[1] = 1.0f; p.scale[2] = 1.0f; // SCALE folded into Q
  gemm_qkv<<<dim3(64, 8, 3), 256, 0, stream>>>(p);

  flash_kernel<<<dim3(8, 64), 512, 0, stream>>>(Qb, Kb, Vb, Og);

  gemm_out_k<<<dim3(64, 8), 256, 0, stream>>>(Og, Wob, bo, (float*)d_out);
}